// Round 3
// baseline (3807.543 us; speedup 1.0000x reference)
//
#include <hip/hip_runtime.h>

// B=32, N_IN=2048, K_OUT=128, C=16, D=16, 3 routing iters.
// Per iter: [k_logits -> p (softmax over k)], [k_acc: MFMA weighted sum -> slice partials],
// [k_fin: slice-reduce + squash]. u_hat recomputed from W each pass (W=268MB < u_hat=537MB).
// MFMA trick: K=32 packed as [c_hi | c_lo]: B=[W_hi|W_lo], A1=[x_hi|x_hi], A2=[x_lo|x_lo]
// -> 2 MFMAs give full (W_hi+W_lo)(x_hi+x_lo) ~= exact fp32 product.

typedef __attribute__((ext_vector_type(8))) short  s16x8;
typedef __attribute__((ext_vector_type(4))) float  f32x4;

#define NSLICE 64

// f32 -> bf16 round-to-nearest-even (inputs finite; no NaN path needed)
__device__ __forceinline__ unsigned bf16rn(float f) {
    const unsigned u = __builtin_bit_cast(unsigned, f);
    return (u + 0x7fffu + ((u >> 16) & 1u)) >> 16;
}
__device__ __forceinline__ unsigned pack2rn(float a, float b) {
    return bf16rn(a) | (bf16rn(b) << 16);
}
// pack two f32 -> two bf16 by truncation (keeps hi+lo exactly consistent)
__device__ __forceinline__ unsigned phi(float a, float b) {
    return (__builtin_bit_cast(unsigned, a) >> 16) | (__builtin_bit_cast(unsigned, b) & 0xffff0000u);
}
// pack two residuals (f - trunc(f)) -> bf16 rn
__device__ __forceinline__ unsigned plo(float a, float b) {
    const float la = a - __builtin_bit_cast(float, __builtin_bit_cast(unsigned, a) & 0xffff0000u);
    const float lb = b - __builtin_bit_cast(float, __builtin_bit_cast(unsigned, b) & 0xffff0000u);
    return pack2rn(la, lb);
}

// out_sl[s][b][k][d] = sum_{i in slice s} w(b,i,k)*u_hat(b,i,k,d); w=p or 1.
// wave = (4-k set) x (32-i slice), all 32 b (2 b-groups). No atomics (private slices).
template<bool USE_P>
__global__ __launch_bounds__(256, 4) void k_acc(const float* __restrict__ W,
                                                const float* __restrict__ x,
                                                const float* __restrict__ p,     // [i][k][b]
                                                float* __restrict__ out_sl)      // [s][b][k][d]
{
    const int w    = blockIdx.x * 4 + (threadIdx.x >> 6);   // 0..2047
    const int lane = threadIdx.x & 63;
    const int n    = lane & 15;          // A: m=b_local ; B: n=d ; C/D: col=d
    const int q    = lane >> 4;
    const int oct  = (q & 1) * 8;        // c-octet this lane packs
    const bool sel = (q < 2);            // quads 0,1: hi half of K; 2,3: lo half
    const int k0    = (w & 31) * 4;
    const int slice = w >> 5;
    const int i0    = slice * 32;

    f32x4 acc[4][2];
#pragma unroll
    for (int kp = 0; kp < 4; ++kp)
#pragma unroll
        for (int bg = 0; bg < 2; ++bg) acc[kp][bg] = f32x4{0.f, 0.f, 0.f, 0.f};
    const f32x4 zero = f32x4{0.f, 0.f, 0.f, 0.f};

#pragma unroll 1
    for (int i = i0; i < i0 + 32; ++i) {
        s16x8 A1[2], A2[2];
#pragma unroll
        for (int bg = 0; bg < 2; ++bg) {
            const float* xp = x + ((size_t)(bg * 16 + n) * 2048 + i) * 16 + oct;
            const float4 x0 = *(const float4*)xp;
            const float4 x1 = *(const float4*)(xp + 4);
            uint4 h, l;
            h.x = phi(x0.x, x0.y); h.y = phi(x0.z, x0.w);
            h.z = phi(x1.x, x1.y); h.w = phi(x1.z, x1.w);
            l.x = plo(x0.x, x0.y); l.y = plo(x0.z, x0.w);
            l.z = plo(x1.x, x1.y); l.w = plo(x1.z, x1.w);
            A1[bg] = __builtin_bit_cast(s16x8, h);
            A2[bg] = __builtin_bit_cast(s16x8, l);
        }
#pragma unroll
        for (int kp = 0; kp < 4; ++kp) {
            const int k = k0 + kp;
            const float* wp = W + (size_t)i * 32768 + (size_t)k * 256 + n * 16 + oct;
            const float4 w0 = *(const float4*)wp;
            const float4 w1 = *(const float4*)(wp + 4);
            const float f[8] = {w0.x, w0.y, w0.z, w0.w, w1.x, w1.y, w1.z, w1.w};
            float t[8];
#pragma unroll
            for (int j = 0; j < 8; ++j) {
                const float hf = __builtin_bit_cast(float, __builtin_bit_cast(unsigned, f[j]) & 0xffff0000u);
                t[j] = sel ? hf : (f[j] - hf);
            }
            uint4 bw;
            bw.x = pack2rn(t[0], t[1]);
            bw.y = pack2rn(t[2], t[3]);
            bw.z = pack2rn(t[4], t[5]);
            bw.w = pack2rn(t[6], t[7]);
            const s16x8 Bf = __builtin_bit_cast(s16x8, bw);
#pragma unroll
            for (int bg = 0; bg < 2; ++bg) {
                if (USE_P) {
                    f32x4 u = __builtin_amdgcn_mfma_f32_16x16x32_bf16(A1[bg], Bf, zero, 0, 0, 0);
                    u       = __builtin_amdgcn_mfma_f32_16x16x32_bf16(A2[bg], Bf, u,    0, 0, 0);
                    const float4 pv = *(const float4*)(p + ((size_t)i * 128 + k) * 32 + bg * 16 + 4 * q);
                    acc[kp][bg].x = fmaf(pv.x, u.x, acc[kp][bg].x);
                    acc[kp][bg].y = fmaf(pv.y, u.y, acc[kp][bg].y);
                    acc[kp][bg].z = fmaf(pv.z, u.z, acc[kp][bg].z);
                    acc[kp][bg].w = fmaf(pv.w, u.w, acc[kp][bg].w);
                } else {
                    acc[kp][bg] = __builtin_amdgcn_mfma_f32_16x16x32_bf16(A1[bg], Bf, acc[kp][bg], 0, 0, 0);
                    acc[kp][bg] = __builtin_amdgcn_mfma_f32_16x16x32_bf16(A2[bg], Bf, acc[kp][bg], 0, 0, 0);
                }
            }
        }
    }
#pragma unroll
    for (int kp = 0; kp < 4; ++kp)
#pragma unroll
        for (int bg = 0; bg < 2; ++bg)
#pragma unroll
            for (int r = 0; r < 4; ++r) {
                const int b = bg * 16 + 4 * q + r;   // C/D row = 4*quad + reg
                out_sl[(((size_t)slice * 32 + b) * 128 + (k0 + kp)) * 16 + n] = acc[kp][bg][r];
            }
}

// thread=(k, bs) bs in [0,8), b = bs+8j, j=0..3 over 2 rounds; V preloaded per round;
// d fully unrolled (immediate-offset W loads off one base).
__global__ __launch_bounds__(1024, 4) void k_logits(const float* __restrict__ W,
                                                    const float* __restrict__ x,
                                                    const float* __restrict__ V,    // [b][k][d]
                                                    const float* __restrict__ Nrm,  // [b][k]
                                                    const float T,
                                                    float* __restrict__ pbuf,       // [i][k][b]
                                                    float* __restrict__ colsum)     // [b][k]
{
    __shared__ float part[16][4][8];
    __shared__ float denom[4][8];
    const int tid  = threadIdx.x;
    const int k    = tid >> 3, bs = tid & 7;
    const int wv   = tid >> 6, lane = tid & 63;
    float nr[4], cs[4], e[4];
#pragma unroll
    for (int j = 0; j < 4; ++j) { nr[j] = Nrm[(bs + 8 * j) * 128 + k]; cs[j] = 0.f; }
    const int i0 = blockIdx.x * 8;
#pragma unroll 1
    for (int ii = 0; ii < 8; ++ii) {
        const int i = i0 + ii;
        const float4* wb = (const float4*)(W + (size_t)i * 32768 + (size_t)k * 256);
#pragma unroll 1
        for (int r = 0; r < 2; ++r) {
            float xa[2][16], va[2][16];
#pragma unroll
            for (int qq = 0; qq < 2; ++qq) {
                const int b = bs + 8 * (2 * r + qq);
                const float4* xp = (const float4*)(x + ((size_t)b * 2048 + i) * 16);
                const float4* vp = (const float4*)(V + ((size_t)b * 128 + k) * 16);
#pragma unroll
                for (int c4 = 0; c4 < 4; ++c4) {
                    const float4 xv = xp[c4], vv = vp[c4];
                    xa[qq][4 * c4] = xv.x; xa[qq][4 * c4 + 1] = xv.y; xa[qq][4 * c4 + 2] = xv.z; xa[qq][4 * c4 + 3] = xv.w;
                    va[qq][4 * c4] = vv.x; va[qq][4 * c4 + 1] = vv.y; va[qq][4 * c4 + 2] = vv.z; va[qq][4 * c4 + 3] = vv.w;
                }
            }
            float s2[2] = {0.f, 0.f}, dt[2] = {0.f, 0.f};
#pragma unroll
            for (int d = 0; d < 16; ++d) {
                float wa[16];
#pragma unroll
                for (int c4 = 0; c4 < 4; ++c4) {
                    const float4 wr = wb[d * 4 + c4];
                    wa[4 * c4] = wr.x; wa[4 * c4 + 1] = wr.y; wa[4 * c4 + 2] = wr.z; wa[4 * c4 + 3] = wr.w;
                }
#pragma unroll
                for (int qq = 0; qq < 2; ++qq) {
                    float u = 0.f;
#pragma unroll
                    for (int c = 0; c < 16; ++c) u = fmaf(wa[c], xa[qq][c], u);
                    s2[qq] = fmaf(u, u, s2[qq]);
                    dt[qq] = fmaf(u, va[qq][d], dt[qq]);
                }
            }
#pragma unroll
            for (int qq = 0; qq < 2; ++qq) {
                const int j  = 2 * r + qq;
                const float ss  = s2[qq];
                const float inv = 1.0f / (0.5f + ss);
                const float scl = sqrtf(ss) * inv;
                const float fq  = ss * ss * inv * inv;
                e[j] = __expf(T * (1.0f - fq) + 2.0f * scl * dt[qq] - nr[j]);
            }
        }
        float sm[4];
#pragma unroll
        for (int j = 0; j < 4; ++j) sm[j] = e[j];
#pragma unroll
        for (int m = 8; m < 64; m <<= 1)
#pragma unroll
            for (int j = 0; j < 4; ++j) sm[j] += __shfl_xor(sm[j], m, 64);
        if (lane < 8) {
#pragma unroll
            for (int j = 0; j < 4; ++j) part[wv][j][lane] = sm[j];
        }
        __syncthreads();
        if (tid < 32) {
            const int j = tid >> 3, b2 = tid & 7;
            float s = 0.f;
#pragma unroll
            for (int w2 = 0; w2 < 16; ++w2) s += part[w2][j][b2];
            denom[j][b2] = s;
        }
        __syncthreads();
#pragma unroll
        for (int j = 0; j < 4; ++j) {
            const float pv = e[j] / denom[j][bs];
            cs[j] += pv;
            pbuf[((size_t)i * 128 + k) * 32 + bs + 8 * j] = pv;
        }
    }
#pragma unroll
    for (int j = 0; j < 4; ++j) atomicAdd(colsum + (bs + 8 * j) * 128 + k, cs[j]);
}

// Sum 64 slices -> v = squash(raw/colsum). thread=(b,k,d), 16 threads per (b,k).
__global__ __launch_bounds__(256) void k_fin(const float* __restrict__ raw_sl,
                                             const float* __restrict__ colsum,
                                             const float* __restrict__ Vprev,
                                             const float* __restrict__ Nprev,
                                             float* __restrict__ Vout,
                                             float* __restrict__ Nout,
                                             float* __restrict__ out,
                                             const int mode)
{
    const int tid = threadIdx.x;
    const int t   = blockIdx.x * 16 + (tid >> 4);
    const int d   = tid & 15;
    float s = 0.f;
#pragma unroll 4
    for (int sl = 0; sl < NSLICE; ++sl) s += raw_sl[(size_t)sl * 65536 + (size_t)t * 16 + d];
    const float invcs = (mode == 0) ? (1.0f / 2048.0f) : 1.0f / colsum[t];
    const float v = s * invcs;
    float s2 = v * v;
#pragma unroll
    for (int m = 1; m < 16; m <<= 1) s2 += __shfl_xor(s2, m, 64);
    const float inv = 1.0f / (0.5f + s2);
    const float scl = sqrtf(s2) * inv;
    if (mode == 0) {
        Vout[(size_t)t * 16 + d] = scl * v;
        if (d == 0) Nout[t] = s2 * scl * scl;
    } else if (mode == 1) {
        Vout[(size_t)t * 16 + d] = Vprev[(size_t)t * 16 + d] + scl * v;
        if (d == 0) Nout[t] = Nprev[t] + s2 * scl * scl;
    } else {
        out[(size_t)t * 16 + d] = scl * v;
        if (d == 0) out[65536 + t] = s2 * inv;   // ||v|| = s2/(0.5+s2)
    }
}

extern "C" void kernel_launch(void* const* d_in, const int* in_sizes, int n_in,
                              void* d_out, int out_size, void* d_ws, size_t ws_size,
                              hipStream_t stream)
{
    const float* x = (const float*)d_in[0];   // [32][2048][16]
    const float* W = (const float*)d_in[3];   // [2048][128][16][16]; labels = arange -> identity gather

    float* ws    = (float*)d_ws;
    float* cs1   = ws;                 // 4096 (zeroed)
    float* cs2   = ws + 4096;          // 4096 (zeroed)
    float* V0    = ws + 8192;          // 65536
    float* VS    = ws + 73728;         // 65536
    float* N1    = ws + 139264;        // 4096
    float* N2    = ws + 143360;        // 4096
    float* pbuf  = ws + 147456;        // 8388608 (32MB) [i][k][b]
    float* slces = ws + 8536064;       // 4194304 (16MB) [s][b][k][d]

    (void)hipMemsetAsync(d_ws, 0, 8192 * sizeof(float), stream);

    k_acc<false><<<512, 256, 0, stream>>>(W, x, nullptr, slces);
    k_fin<<<256, 256, 0, stream>>>(slces, nullptr, nullptr, nullptr, V0, N1, nullptr, 0);

    k_logits<<<256, 1024, 0, stream>>>(W, x, V0, N1, 1.0f, pbuf, cs1);
    k_acc<true><<<512, 256, 0, stream>>>(W, x, pbuf, slces);
    k_fin<<<256, 256, 0, stream>>>(slces, cs1, V0, N1, VS, N2, nullptr, 1);

    k_logits<<<256, 1024, 0, stream>>>(W, x, VS, N2, 2.0f, pbuf, cs2);
    k_acc<true><<<512, 256, 0, stream>>>(W, x, pbuf, slces);
    k_fin<<<256, 256, 0, stream>>>(slces, cs2, nullptr, nullptr, nullptr, nullptr, (float*)d_out, 2);
}

// Round 4
// 1451.090 us; speedup vs baseline: 2.6239x; 2.6239x over previous
//
#include <hip/hip_runtime.h>

// B=32, N_IN=2048, K_OUT=128, C=16, D=16, 3 routing iters.
// Per iter: [k_logits: MFMA u-tiles -> softmax p], [k_acc: MFMA weighted sum -> slice partials],
// [k_fin: slice-reduce + squash -> transposed tables / output].
// u_hat recomputed from W each pass (W=268MB < u_hat=537MB). MFMA hi/lo trick (verified R3):
// K=32 packed as [c_hi | c_lo]: B=[W_hi|W_lo], A1=[x_hi|x_hi], A2=[x_lo|x_lo]
// -> 2 MFMAs give the full (W_hi+W_lo)(x_hi+x_lo) ~= exact fp32 product.
// NOTE: no second __launch_bounds__ arg anywhere -- R3 showed it acts as a hard VGPR cap
// (1024,4 -> 64 VGPR -> 2 GB/dispatch scratch spill).

typedef __attribute__((ext_vector_type(8))) short  s16x8;
typedef __attribute__((ext_vector_type(4))) float  f32x4;

#define NSLICE 64

__device__ __forceinline__ unsigned bf16rn(float f) {
    const unsigned u = __builtin_bit_cast(unsigned, f);
    return (u + 0x7fffu + ((u >> 16) & 1u)) >> 16;
}
__device__ __forceinline__ unsigned pack2rn(float a, float b) {
    return bf16rn(a) | (bf16rn(b) << 16);
}
__device__ __forceinline__ unsigned phi(float a, float b) {   // truncation hi-pack
    return (__builtin_bit_cast(unsigned, a) >> 16) | (__builtin_bit_cast(unsigned, b) & 0xffff0000u);
}
__device__ __forceinline__ unsigned plo(float a, float b) {   // residual lo-pack
    const float la = a - __builtin_bit_cast(float, __builtin_bit_cast(unsigned, a) & 0xffff0000u);
    const float lb = b - __builtin_bit_cast(float, __builtin_bit_cast(unsigned, b) & 0xffff0000u);
    return pack2rn(la, lb);
}

// A-frags for one b-group: A1=[x_hi|x_hi], A2=[x_lo|x_lo]; xp points at x[b][i][oct]
__device__ __forceinline__ void pack_A(const float* __restrict__ xp, s16x8& A1, s16x8& A2) {
    const float4 x0 = *(const float4*)xp;
    const float4 x1 = *(const float4*)(xp + 4);
    uint4 h, l;
    h.x = phi(x0.x, x0.y); h.y = phi(x0.z, x0.w);
    h.z = phi(x1.x, x1.y); h.w = phi(x1.z, x1.w);
    l.x = plo(x0.x, x0.y); l.y = plo(x0.z, x0.w);
    l.z = plo(x1.x, x1.y); l.w = plo(x1.z, x1.w);
    A1 = __builtin_bit_cast(s16x8, h);
    A2 = __builtin_bit_cast(s16x8, l);
}

// B-frag [W_hi|W_lo]: wp points at W[i][k][d=n][oct]; sel=true -> hi half lanes
__device__ __forceinline__ s16x8 pack_B(const float* __restrict__ wp, bool sel) {
    const float4 w0 = *(const float4*)wp;
    const float4 w1 = *(const float4*)(wp + 4);
    const float f[8] = {w0.x, w0.y, w0.z, w0.w, w1.x, w1.y, w1.z, w1.w};
    float t[8];
#pragma unroll
    for (int j = 0; j < 8; ++j) {
        const float hf = __builtin_bit_cast(float, __builtin_bit_cast(unsigned, f[j]) & 0xffff0000u);
        t[j] = sel ? hf : (f[j] - hf);
    }
    uint4 bw;
    bw.x = pack2rn(t[0], t[1]);
    bw.y = pack2rn(t[2], t[3]);
    bw.z = pack2rn(t[4], t[5]);
    bw.w = pack2rn(t[6], t[7]);
    return __builtin_bit_cast(s16x8, bw);
}

__device__ __forceinline__ f32x4 sx4(f32x4 v, int m) {
    f32x4 r;
    r.x = __shfl_xor(v.x, m, 64);
    r.y = __shfl_xor(v.y, m, 64);
    r.z = __shfl_xor(v.z, m, 64);
    r.w = __shfl_xor(v.w, m, 64);
    return r;
}

// ---------------------------------------------------------------------------
// out_sl[s][b][k][d] = sum_{i in slice s} w(b,i,k)*u_hat(b,i,k,d); w=p or 1.
// wave = (2-k set) x (32-i slice), all 32 b. 4096 waves (4/SIMD). No atomics.
template<bool USE_P>
__global__ __launch_bounds__(256) void k_acc(const float* __restrict__ W,
                                             const float* __restrict__ x,
                                             const float* __restrict__ p,     // [i][k][b]
                                             float* __restrict__ out_sl)      // [s][b][k][d]
{
    const int w    = blockIdx.x * 4 + (threadIdx.x >> 6);   // 0..4095
    const int lane = threadIdx.x & 63;
    const int n    = lane & 15;          // A row m=b_local ; B col n=d ; C/D col=d
    const int q    = lane >> 4;
    const int oct  = (q & 1) * 8;
    const bool sel = (q < 2);
    const int k0    = (w & 63) * 2;
    const int slice = w >> 6;            // 0..63
    const int i0    = slice * 32;

    const f32x4 zero = {0.f, 0.f, 0.f, 0.f};
    f32x4 acc[2][2];
#pragma unroll
    for (int kp = 0; kp < 2; ++kp)
#pragma unroll
        for (int bg = 0; bg < 2; ++bg) acc[kp][bg] = zero;

#pragma unroll 1
    for (int i = i0; i < i0 + 32; ++i) {
        s16x8 A1[2], A2[2];
#pragma unroll
        for (int bg = 0; bg < 2; ++bg)
            pack_A(x + ((size_t)(bg * 16 + n) * 2048 + i) * 16 + oct, A1[bg], A2[bg]);
#pragma unroll
        for (int kp = 0; kp < 2; ++kp) {
            const int k = k0 + kp;
            const s16x8 Bf = pack_B(W + (size_t)i * 32768 + (size_t)k * 256 + n * 16 + oct, sel);
#pragma unroll
            for (int bg = 0; bg < 2; ++bg) {
                if (USE_P) {
                    f32x4 u = __builtin_amdgcn_mfma_f32_16x16x32_bf16(A1[bg], Bf, zero, 0, 0, 0);
                    u       = __builtin_amdgcn_mfma_f32_16x16x32_bf16(A2[bg], Bf, u,    0, 0, 0);
                    const float4 pv = *(const float4*)(p + ((size_t)i * 128 + k) * 32 + bg * 16 + 4 * q);
                    acc[kp][bg].x = fmaf(pv.x, u.x, acc[kp][bg].x);
                    acc[kp][bg].y = fmaf(pv.y, u.y, acc[kp][bg].y);
                    acc[kp][bg].z = fmaf(pv.z, u.z, acc[kp][bg].z);
                    acc[kp][bg].w = fmaf(pv.w, u.w, acc[kp][bg].w);
                } else {
                    acc[kp][bg] = __builtin_amdgcn_mfma_f32_16x16x32_bf16(A1[bg], Bf, acc[kp][bg], 0, 0, 0);
                    acc[kp][bg] = __builtin_amdgcn_mfma_f32_16x16x32_bf16(A2[bg], Bf, acc[kp][bg], 0, 0, 0);
                }
            }
        }
    }
#pragma unroll
    for (int kp = 0; kp < 2; ++kp)
#pragma unroll
        for (int bg = 0; bg < 2; ++bg)
#pragma unroll
            for (int r = 0; r < 4; ++r) {
                const int b = bg * 16 + 4 * q + r;   // C/D row = 4*quad + reg (verified R3)
                out_sl[(((size_t)slice * 32 + b) * 128 + (k0 + kp)) * 16 + n] = acc[kp][bg][r];
            }
}

// ---------------------------------------------------------------------------
// MFMA logits: block = 8 waves, wave wv covers k = wv*16+kp (16 k's), 4 i's per block.
// Per (i,kp): u tile via MFMA pair; s2 += u*u, dot += u*V in-lane; butterfly over 16
// d-lanes; exp; block softmax over all 128 k via LDS; p written [i][k][b] (float4).
__global__ __launch_bounds__(512) void k_logits(const float* __restrict__ W,
                                                const float* __restrict__ x,
                                                const float* __restrict__ Vbt,  // [k][d][b]
                                                const float* __restrict__ Nt,   // [k][b]
                                                const float T,
                                                float* __restrict__ pbuf,       // [i][k][b]
                                                float* __restrict__ colsum)     // [b][k]
{
    __shared__ __align__(16) float e_s[8][16][32];
    __shared__ __align__(16) float den_s[8][32];
    __shared__ float denom_s[32];
    const int tid  = threadIdx.x;
    const int wv   = tid >> 6, lane = tid & 63;
    const int n    = lane & 15, q = lane >> 4;
    const int oct  = (q & 1) * 8;
    const bool sel = (q < 2);
    const f32x4 zero = {0.f, 0.f, 0.f, 0.f};

    // p-write phase mapping: thread -> (k = tid/4, b0 = (tid&3)*8)
    const int pk = tid >> 2;
    const int pb = (tid & 3) * 8;
    float cs[8];
#pragma unroll
    for (int j = 0; j < 8; ++j) cs[j] = 0.f;

    const int i0 = blockIdx.x * 4;
#pragma unroll 1
    for (int ii = 0; ii < 4; ++ii) {
        const int i = i0 + ii;
        s16x8 A1[2], A2[2];
#pragma unroll
        for (int bg = 0; bg < 2; ++bg)
            pack_A(x + ((size_t)(bg * 16 + n) * 2048 + i) * 16 + oct, A1[bg], A2[bg]);

        f32x4 den[2] = {zero, zero};
#pragma unroll
        for (int kp = 0; kp < 16; ++kp) {
            const int k = wv * 16 + kp;
            const s16x8 Bf = pack_B(W + (size_t)i * 32768 + (size_t)k * 256 + n * 16 + oct, sel);
            f32x4 s2v[2], dtv[2];
#pragma unroll
            for (int bg = 0; bg < 2; ++bg) {
                f32x4 u = __builtin_amdgcn_mfma_f32_16x16x32_bf16(A1[bg], Bf, zero, 0, 0, 0);
                u       = __builtin_amdgcn_mfma_f32_16x16x32_bf16(A2[bg], Bf, u,    0, 0, 0);
                const float4 Vv = *(const float4*)(Vbt + ((size_t)k * 16 + n) * 32 + bg * 16 + 4 * q);
                s2v[bg].x = u.x * u.x; s2v[bg].y = u.y * u.y; s2v[bg].z = u.z * u.z; s2v[bg].w = u.w * u.w;
                dtv[bg].x = u.x * Vv.x; dtv[bg].y = u.y * Vv.y; dtv[bg].z = u.z * Vv.z; dtv[bg].w = u.w * Vv.w;
            }
#pragma unroll
            for (int m = 1; m < 16; m <<= 1) {
#pragma unroll
                for (int bg = 0; bg < 2; ++bg) {
                    s2v[bg] += sx4(s2v[bg], m);
                    dtv[bg] += sx4(dtv[bg], m);
                }
            }
#pragma unroll
            for (int bg = 0; bg < 2; ++bg) {
                const float4 Nv = *(const float4*)(Nt + (size_t)k * 32 + bg * 16 + 4 * q);
                f32x4 e;
#pragma unroll
                for (int r = 0; r < 4; ++r) {
                    const float ss  = s2v[bg][r];
                    const float inv = 1.0f / (0.5f + ss);
                    const float scl = sqrtf(ss) * inv;
                    const float fq  = ss * ss * inv * inv;
                    const float Nr  = (r == 0) ? Nv.x : (r == 1) ? Nv.y : (r == 2) ? Nv.z : Nv.w;
                    e[r] = __expf(T * (1.0f - fq) + 2.0f * scl * dtv[bg][r] - Nr);
                }
                den[bg] += e;
                if (n == 0) *(f32x4*)&e_s[wv][kp][bg * 16 + 4 * q] = e;
            }
        }
        if (n == 0) {
#pragma unroll
            for (int bg = 0; bg < 2; ++bg)
                *(f32x4*)&den_s[wv][bg * 16 + 4 * q] = den[bg];
        }
        __syncthreads();
        if (tid < 32) {
            float s = 0.f;
#pragma unroll
            for (int w2 = 0; w2 < 8; ++w2) s += den_s[w2][tid];
            denom_s[tid] = s;
        }
        __syncthreads();
        {
            const float4 e0 = *(const float4*)&e_s[pk >> 4][pk & 15][pb];
            const float4 e1 = *(const float4*)&e_s[pk >> 4][pk & 15][pb + 4];
            const float4 d0 = *(const float4*)&denom_s[pb];
            const float4 d1 = *(const float4*)&denom_s[pb + 4];
            float4 p0, p1;
            p0.x = e0.x / d0.x; p0.y = e0.y / d0.y; p0.z = e0.z / d0.z; p0.w = e0.w / d0.w;
            p1.x = e1.x / d1.x; p1.y = e1.y / d1.y; p1.z = e1.z / d1.z; p1.w = e1.w / d1.w;
            cs[0] += p0.x; cs[1] += p0.y; cs[2] += p0.z; cs[3] += p0.w;
            cs[4] += p1.x; cs[5] += p1.y; cs[6] += p1.z; cs[7] += p1.w;
            *(float4*)(pbuf + ((size_t)i * 128 + pk) * 32 + pb)     = p0;
            *(float4*)(pbuf + ((size_t)i * 128 + pk) * 32 + pb + 4) = p1;
        }
        __syncthreads();
    }
#pragma unroll
    for (int j = 0; j < 8; ++j) atomicAdd(colsum + (size_t)(pb + j) * 128 + pk, cs[j]);
}

// ---------------------------------------------------------------------------
// Sum 64 slices -> v = squash(raw/colsum); write transposed tables (mode 0/1) or output.
__global__ __launch_bounds__(256) void k_fin(const float* __restrict__ raw_sl,
                                             const float* __restrict__ colsum,
                                             const float* __restrict__ Vbt_prev,
                                             const float* __restrict__ Nt_prev,
                                             float* __restrict__ Vbt_out,
                                             float* __restrict__ Nt_out,
                                             float* __restrict__ out,
                                             const int mode)
{
    const int tid = threadIdx.x;
    const int t   = blockIdx.x * 16 + (tid >> 4);   // (b,k): b=t>>7, k=t&127
    const int d   = tid & 15;
    const int b   = t >> 7, k = t & 127;
    float s = 0.f;
#pragma unroll 4
    for (int sl = 0; sl < NSLICE; ++sl) s += raw_sl[(size_t)sl * 65536 + (size_t)t * 16 + d];
    const float invcs = (mode == 0) ? (1.0f / 2048.0f) : 1.0f / colsum[t];
    const float v = s * invcs;
    float s2 = v * v;
#pragma unroll
    for (int m = 1; m < 16; m <<= 1) s2 += __shfl_xor(s2, m, 64);
    const float inv = 1.0f / (0.5f + s2);
    const float scl = sqrtf(s2) * inv;
    if (mode == 0) {
        Vbt_out[((size_t)k * 16 + d) * 32 + b] = scl * v;
        if (d == 0) Nt_out[(size_t)k * 32 + b] = s2 * scl * scl;
    } else if (mode == 1) {
        Vbt_out[((size_t)k * 16 + d) * 32 + b] = Vbt_prev[((size_t)k * 16 + d) * 32 + b] + scl * v;
        if (d == 0) Nt_out[(size_t)k * 32 + b] = Nt_prev[(size_t)k * 32 + b] + s2 * scl * scl;
    } else {
        out[(size_t)t * 16 + d] = scl * v;
        if (d == 0) out[65536 + t] = s2 * inv;   // ||v|| = s2/(0.5+s2)
    }
}

extern "C" void kernel_launch(void* const* d_in, const int* in_sizes, int n_in,
                              void* d_out, int out_size, void* d_ws, size_t ws_size,
                              hipStream_t stream)
{
    const float* x = (const float*)d_in[0];   // [32][2048][16]
    const float* W = (const float*)d_in[3];   // [2048][128][16][16]; labels = arange -> identity

    float* ws    = (float*)d_ws;
    float* cs1   = ws;                 // 4096 (zeroed)
    float* cs2   = ws + 4096;          // 4096 (zeroed)
    float* Vbt0  = ws + 8192;          // 65536  [k][d][b]
    float* VSbt  = ws + 73728;         // 65536
    float* N1t   = ws + 139264;        // 4096   [k][b]
    float* N2t   = ws + 143360;        // 4096
    float* pbuf  = ws + 147456;        // 8388608 (32MB) [i][k][b]
    float* slces = ws + 8536064;       // 4194304 (16MB) [s][b][k][d]

    (void)hipMemsetAsync(d_ws, 0, 8192 * sizeof(float), stream);

    // iter 0: v0 = squash(mean_i u_hat)
    k_acc<false><<<1024, 256, 0, stream>>>(W, x, nullptr, slces);
    k_fin<<<256, 256, 0, stream>>>(slces, nullptr, nullptr, nullptr, Vbt0, N1t, nullptr, 0);
    // iter 1
    k_logits<<<512, 512, 0, stream>>>(W, x, Vbt0, N1t, 1.0f, pbuf, cs1);
    k_acc<true><<<1024, 256, 0, stream>>>(W, x, pbuf, slces);
    k_fin<<<256, 256, 0, stream>>>(slces, cs1, Vbt0, N1t, VSbt, N2t, nullptr, 1);
    // iter 2: b2 = dd0+dd1 via summed tables VS=v0+v1, N2=||v0||^2+||v1||^2
    k_logits<<<512, 512, 0, stream>>>(W, x, VSbt, N2t, 2.0f, pbuf, cs2);
    k_acc<true><<<1024, 256, 0, stream>>>(W, x, pbuf, slces);
    k_fin<<<256, 256, 0, stream>>>(slces, cs2, nullptr, nullptr, nullptr, nullptr, (float*)d_out, 2);
}